// Round 3
// baseline (774.705 us; speedup 1.0000x reference)
//
#include <hip/hip_runtime.h>
#include <stdint.h>

typedef unsigned short ushort_t;
typedef __attribute__((ext_vector_type(4))) float f32x4;
typedef __attribute__((ext_vector_type(8))) short s16x8;

#define S1_ELEMS ((size_t)1568*64*512)   // 51,380,224 elements per q/k/v/x/ao buffer

// ---------- bf16 helpers (RNE)
__device__ __forceinline__ ushort_t f2bf(float f) {
  unsigned u = __builtin_bit_cast(unsigned, f);
  u = u + 0x7fffu + ((u >> 16) & 1u);
  return (ushort_t)(u >> 16);
}

// ---------- async global->LDS, 16B per lane (dest = uniform base + lane*16)
__device__ __forceinline__ void gl_lds16(const ushort_t* g, ushort_t* l) {
  typedef __attribute__((address_space(1))) void gvoid;
  typedef __attribute__((address_space(3))) void lvoid;
  __builtin_amdgcn_global_load_lds((gvoid*)(ushort_t*)g, (lvoid*)l, 16, 0, 0);
}

// ---------- kernel 1: f32 -> bf16 (hi only)
__global__ void k_convert_hi(const float* __restrict__ src, ushort_t* __restrict__ hi, long n4) {
  long i = (long)blockIdx.x * blockDim.x + threadIdx.x;
  long stride = (long)gridDim.x * blockDim.x;
  for (; i < n4; i += stride) {
    float4 v = ((const float4*)src)[i];
    ushort4 h;
    h.x = f2bf(v.x); h.y = f2bf(v.y); h.z = f2bf(v.z); h.w = f2bf(v.w);
    ((ushort4*)hi)[i] = h;
  }
}

// ---------- kernel 1b: precompute bias[h][rr][cc] = table[rel_idx[rr,cc]*16+h]
__global__ void k_bias(const float* __restrict__ table, const int* __restrict__ rel_idx,
                       float* __restrict__ bias) {
  int i = blockIdx.x * 256 + threadIdx.x;   // 65536 total
  int h = i >> 12, rc = i & 4095;
  bias[i] = table[rel_idx[rc] * 16 + h];
}

// ---------- kernel 2: QKV GEMM, plain bf16, 2-phase double-buffered prefetch.
// 128x128 tile, BK=64, 4 waves (2x2 of 64x64), fragment-linear LDS (0 conflicts).
__global__ __launch_bounds__(256) void k_gemm_qkv(
    const ushort_t* __restrict__ xh, const ushort_t* __restrict__ wh,
    ushort_t* __restrict__ qh, ushort_t* __restrict__ kh, ushort_t* __restrict__ vt) {
  __shared__ __align__(16) ushort_t lds0[2][16384];  // [dbuf][A 8192 | B 8192] = 64 KiB
  const int tid = threadIdx.x, w = tid >> 6, lane = tid & 63;
  const int g = lane >> 4, l15 = lane & 15;
  // bijective XCD swizzle: nwg = 9408 = 8*1176
  int flat = blockIdx.x;
  int swz = (flat & 7) * 1176 + (flat >> 3);
  int bx = swz % 12, by = swz / 12;
  const int wm = w >> 1, wn = w & 1;

  f32x4 acc[4][4];
  #pragma unroll
  for (int r = 0; r < 4; r++)
    #pragma unroll
    for (int c = 0; c < 4; c++) acc[r][c] = (f32x4){0.f,0.f,0.f,0.f};

  // staging: 32 subtile-issues (A:16, B:16), 8 per wave.
  // subtile ti = s*2+u (s=row-block of 16, u=k-sub of 32); lane L covers
  // global row s*16+(L&15), k-chunk u*32+(L>>4)*8 -> LDS slot ti*512 + L*8.
  const ushort_t* sptr[8]; int loff[8];
  #pragma unroll
  for (int q = 0; q < 8; q++) {
    int gq = w*8 + q;
    int buf = gq >> 4, ti = gq & 15, s = ti >> 1, u = ti & 1;
    const ushort_t* src = buf ? wh : xh;
    size_t rb = buf ? (size_t)bx*128 : (size_t)by*128;
    sptr[q] = src + (rb + (size_t)(s*16 + l15))*512 + u*32 + g*8;
    loff[q] = buf*8192 + ti*512;
  }

  // prologue: stage k-tile 0 into buf 0
  #pragma unroll
  for (int q = 0; q < 8; q++) gl_lds16(sptr[q], &lds0[0][loff[q]]);
  __syncthreads();

  int cur = 0;
  for (int kk = 0; kk < 512; kk += 64) {
    // issue next tile's loads first — they fly under this tile's compute
    if (kk < 448) {
      #pragma unroll
      for (int q = 0; q < 8; q++) gl_lds16(sptr[q] + kk + 64, &lds0[cur ^ 1][loff[q]]);
    }
    #pragma unroll
    for (int u = 0; u < 2; u++) {
      s16x8 af[4], bf[4];
      #pragma unroll
      for (int t = 0; t < 4; t++) {
        af[t] = *(const s16x8*)&lds0[cur][((wm*4 + t)*2 + u)*512 + lane*8];
        bf[t] = *(const s16x8*)&lds0[cur][8192 + ((wn*4 + t)*2 + u)*512 + lane*8];
      }
      #pragma unroll
      for (int r = 0; r < 4; r++)
        #pragma unroll
        for (int c = 0; c < 4; c++)
          acc[r][c] = __builtin_amdgcn_mfma_f32_16x16x32_bf16(af[r], bf[c], acc[r][c], 0, 0, 0);
    }
    __syncthreads();   // drains vmcnt(0): next tile staged; lgkm: reads of cur done
    cur ^= 1;
  }

  // epilogue: scatter to q[b,h,n,d], k[b,h,n,d], vT[b,h,d,n]
  #pragma unroll
  for (int r = 0; r < 4; r++)
    #pragma unroll
    for (int c = 0; c < 4; c++)
      #pragma unroll
      for (int j = 0; j < 4; j++) {
        int mrow = by*128 + wm*64 + r*16 + g*4 + j;
        int ncol = bx*128 + wn*64 + c*16 + l15;
        int sel = ncol >> 9, h = (ncol >> 5) & 15, d = ncol & 31;
        int b = mrow >> 6, n = mrow & 63;
        ushort_t hv = f2bf(acc[r][c][j]);
        if (sel == 0)      qh[(((size_t)b*16 + h)*64 + n)*32 + d] = hv;
        else if (sel == 1) kh[(((size_t)b*16 + h)*64 + n)*32 + d] = hv;
        else               vt[(((size_t)b*16 + h)*32 + d)*64 + n] = hv;
      }
}

// ---------- kernel 3: per-(b,h) attention, plain bf16, one wave per head-window.
__global__ __launch_bounds__(256) void k_attn(
    const ushort_t* __restrict__ qh, const ushort_t* __restrict__ kh,
    const ushort_t* __restrict__ vt, const float* __restrict__ bias,
    ushort_t* __restrict__ aoh) {
  __shared__ ushort_t plds[4][64*72];
  const int tid = threadIdx.x, w = tid >> 6, lane = tid & 63;
  const int g = lane >> 4, l15 = lane & 15;
  const int gw = blockIdx.x * 4 + w;      // 0 .. 25087
  const int b = gw >> 4, h = gw & 15;
  const size_t base = (size_t)(b*16 + h) * 2048;

  s16x8 qf[4], kf[4];
  #pragma unroll
  for (int t = 0; t < 4; t++) {
    size_t o = base + (size_t)(t*16 + l15)*32 + g*8;
    qf[t] = *(const s16x8*)&qh[o];
    kf[t] = *(const s16x8*)&kh[o];
  }
  // V^T fragments: vf[kt][nt] lane (g,l15) = V[m=kt*32+g*8+i][d=nt*16+l15]
  s16x8 vf[2][2];
  #pragma unroll
  for (int kt = 0; kt < 2; kt++)
    #pragma unroll
    for (int nt = 0; nt < 2; nt++)
      vf[kt][nt] = *(const s16x8*)&vt[base + (size_t)(nt*16 + l15)*64 + kt*32 + g*8];

  // S = Q@K^T
  f32x4 s[4][4];
  #pragma unroll
  for (int r = 0; r < 4; r++)
    #pragma unroll
    for (int c = 0; c < 4; c++) s[r][c] = (f32x4){0.f,0.f,0.f,0.f};
  #pragma unroll
  for (int r = 0; r < 4; r++)
    #pragma unroll
    for (int c = 0; c < 4; c++)
      s[r][c] = __builtin_amdgcn_mfma_f32_16x16x32_bf16(qf[r], kf[c], s[r][c], 0, 0, 0);

  // scale + precomputed relative-position bias
  const float invs = 0.17677669529663687f;  // 1/sqrt(32)
  const float* bh_ = bias + ((size_t)h << 12);
  #pragma unroll
  for (int r = 0; r < 4; r++)
    #pragma unroll
    for (int c = 0; c < 4; c++)
      #pragma unroll
      for (int j = 0; j < 4; j++) {
        int rr = r*16 + g*4 + j, cc = c*16 + l15;
        s[r][c][j] = s[r][c][j]*invs + bh_[rr*64 + cc];
      }

  // softmax over cc (4 in-reg cols x 16 lanes of the same 16-lane group)
  #pragma unroll
  for (int r = 0; r < 4; r++)
    #pragma unroll
    for (int j = 0; j < 4; j++) {
      float mx = fmaxf(fmaxf(s[r][0][j], s[r][1][j]), fmaxf(s[r][2][j], s[r][3][j]));
      mx = fmaxf(mx, __shfl_xor(mx, 1));
      mx = fmaxf(mx, __shfl_xor(mx, 2));
      mx = fmaxf(mx, __shfl_xor(mx, 4));
      mx = fmaxf(mx, __shfl_xor(mx, 8));
      float p0 = __expf(s[r][0][j]-mx), p1 = __expf(s[r][1][j]-mx);
      float p2 = __expf(s[r][2][j]-mx), p3 = __expf(s[r][3][j]-mx);
      float sum = p0 + p1 + p2 + p3;
      sum += __shfl_xor(sum, 1);
      sum += __shfl_xor(sum, 2);
      sum += __shfl_xor(sum, 4);
      sum += __shfl_xor(sum, 8);
      float rv = 1.0f / sum;
      s[r][0][j] = p0*rv; s[r][1][j] = p1*rv; s[r][2][j] = p2*rv; s[r][3][j] = p3*rv;
    }

  // P -> LDS (acc layout, pad 72) then re-read in A-fragment layout
  ushort_t* P = plds[w];
  #pragma unroll
  for (int r = 0; r < 4; r++)
    #pragma unroll
    for (int c = 0; c < 4; c++)
      #pragma unroll
      for (int j = 0; j < 4; j++) {
        int rr = r*16 + g*4 + j, cc = c*16 + l15;
        P[rr*72 + cc] = f2bf(s[r][c][j]);
      }
  s16x8 pf[4][2];
  #pragma unroll
  for (int ta = 0; ta < 4; ta++)
    #pragma unroll
    for (int kt = 0; kt < 2; kt++)
      pf[ta][kt] = *(const s16x8*)&P[(ta*16 + l15)*72 + kt*32 + g*8];

  // out = P @ V
  f32x4 o[4][2];
  #pragma unroll
  for (int ta = 0; ta < 4; ta++)
    #pragma unroll
    for (int nt = 0; nt < 2; nt++) o[ta][nt] = (f32x4){0.f,0.f,0.f,0.f};
  #pragma unroll
  for (int ta = 0; ta < 4; ta++)
    #pragma unroll
    for (int nt = 0; nt < 2; nt++)
      #pragma unroll
      for (int kt = 0; kt < 2; kt++)
        o[ta][nt] = __builtin_amdgcn_mfma_f32_16x16x32_bf16(pf[ta][kt], vf[kt][nt], o[ta][nt], 0, 0, 0);

  // write attention-out bf16 in [m, h*32+d] layout
  #pragma unroll
  for (int ta = 0; ta < 4; ta++)
    #pragma unroll
    for (int nt = 0; nt < 2; nt++)
      #pragma unroll
      for (int j = 0; j < 4; j++) {
        int rr = ta*16 + g*4 + j, dd = nt*16 + l15;
        aoh[((size_t)b*64 + rr)*512 + h*32 + dd] = f2bf(o[ta][nt][j]);
      }
}

// ---------- kernel 4: proj GEMM, plain bf16, 2-phase prefetch, + bias, f32 out.
__global__ __launch_bounds__(256) void k_gemm_proj(
    const ushort_t* __restrict__ ah, const ushort_t* __restrict__ wh,
    const float* __restrict__ pb, float* __restrict__ out) {
  __shared__ __align__(16) ushort_t lds0[2][16384];
  const int tid = threadIdx.x, w = tid >> 6, lane = tid & 63;
  const int g = lane >> 4, l15 = lane & 15;
  int flat = blockIdx.x;                    // nwg = 3136 = 8*392
  int swz = (flat & 7) * 392 + (flat >> 3);
  int bx = swz & 3, by = swz >> 2;
  const int wm = w >> 1, wn = w & 1;

  f32x4 acc[4][4];
  #pragma unroll
  for (int r = 0; r < 4; r++)
    #pragma unroll
    for (int c = 0; c < 4; c++) acc[r][c] = (f32x4){0.f,0.f,0.f,0.f};

  const ushort_t* sptr[8]; int loff[8];
  #pragma unroll
  for (int q = 0; q < 8; q++) {
    int gq = w*8 + q;
    int buf = gq >> 4, ti = gq & 15, s = ti >> 1, u = ti & 1;
    const ushort_t* src = buf ? wh : ah;
    size_t rb = buf ? (size_t)bx*128 : (size_t)by*128;
    sptr[q] = src + (rb + (size_t)(s*16 + l15))*512 + u*32 + g*8;
    loff[q] = buf*8192 + ti*512;
  }

  #pragma unroll
  for (int q = 0; q < 8; q++) gl_lds16(sptr[q], &lds0[0][loff[q]]);
  __syncthreads();

  int cur = 0;
  for (int kk = 0; kk < 512; kk += 64) {
    if (kk < 448) {
      #pragma unroll
      for (int q = 0; q < 8; q++) gl_lds16(sptr[q] + kk + 64, &lds0[cur ^ 1][loff[q]]);
    }
    #pragma unroll
    for (int u = 0; u < 2; u++) {
      s16x8 af[4], bf[4];
      #pragma unroll
      for (int t = 0; t < 4; t++) {
        af[t] = *(const s16x8*)&lds0[cur][((wm*4 + t)*2 + u)*512 + lane*8];
        bf[t] = *(const s16x8*)&lds0[cur][8192 + ((wn*4 + t)*2 + u)*512 + lane*8];
      }
      #pragma unroll
      for (int r = 0; r < 4; r++)
        #pragma unroll
        for (int c = 0; c < 4; c++)
          acc[r][c] = __builtin_amdgcn_mfma_f32_16x16x32_bf16(af[r], bf[c], acc[r][c], 0, 0, 0);
    }
    __syncthreads();
    cur ^= 1;
  }

  #pragma unroll
  for (int r = 0; r < 4; r++)
    #pragma unroll
    for (int c = 0; c < 4; c++)
      #pragma unroll
      for (int j = 0; j < 4; j++) {
        int mrow = by*128 + wm*64 + r*16 + g*4 + j;
        int ncol = bx*128 + wn*64 + c*16 + l15;
        out[(size_t)mrow*512 + ncol] = acc[r][c][j] + pb[ncol];
      }
}

extern "C" void kernel_launch(void* const* d_in, const int* in_sizes, int n_in,
                              void* d_out, int out_size, void* d_ws, size_t ws_size,
                              hipStream_t stream) {
  const float* x      = (const float*)d_in[0];
  const float* qkv_w  = (const float*)d_in[1];
  const float* table  = (const float*)d_in[2];
  const float* proj_w = (const float*)d_in[3];
  const float* proj_b = (const float*)d_in[4];
  const int*   rel_idx = (const int*)d_in[5];

  const size_t S1 = S1_ELEMS;
  const size_t need = (4*S1 + 786432 + 262144)*sizeof(ushort_t) + 65536*sizeof(float);
  if (ws_size < need) return;

  ushort_t* qh  = (ushort_t*)d_ws;
  ushort_t* kh  = qh + S1;
  ushort_t* vt  = kh + S1;
  ushort_t* xh  = vt + S1;        // reused as attention-out after QKV GEMM
  ushort_t* wqh = xh + S1;
  ushort_t* wph = wqh + 786432;
  float*    bias = (float*)(wph + 262144);
  ushort_t* aoh = xh;

  k_convert_hi<<<2048, 256, 0, stream>>>(x, xh, (long)(S1/4));
  k_convert_hi<<<768, 256, 0, stream>>>(qkv_w, wqh, 196608);
  k_convert_hi<<<256, 256, 0, stream>>>(proj_w, wph, 65536);
  k_bias<<<256, 256, 0, stream>>>(table, rel_idx, bias);
  k_gemm_qkv<<<9408, 256, 0, stream>>>(xh, wqh, qh, kh, vt);
  k_attn<<<6272, 256, 0, stream>>>(qh, kh, vt, bias, aoh);
  k_gemm_proj<<<3136, 256, 0, stream>>>(aoh, wph, proj_b, (float*)d_out);
}

// Round 4
// 666.314 us; speedup vs baseline: 1.1627x; 1.1627x over previous
//
#include <hip/hip_runtime.h>
#include <stdint.h>

typedef unsigned short ushort_t;
typedef __attribute__((ext_vector_type(4))) float f32x4;
typedef __attribute__((ext_vector_type(8))) short s16x8;

#define S1_ELEMS ((size_t)1568*64*512)   // 51,380,224 elements per q/k/v/x/ao buffer

// ---------- bf16 helpers (RNE)
__device__ __forceinline__ ushort_t f2bf(float f) {
  unsigned u = __builtin_bit_cast(unsigned, f);
  u = u + 0x7fffu + ((u >> 16) & 1u);
  return (ushort_t)(u >> 16);
}

// ---------- async global->LDS, 16B per lane (dest = uniform base + lane*16)
__device__ __forceinline__ void gl_lds16(const ushort_t* g, ushort_t* l) {
  typedef __attribute__((address_space(1))) void gvoid;
  typedef __attribute__((address_space(3))) void lvoid;
  __builtin_amdgcn_global_load_lds((gvoid*)(ushort_t*)g, (lvoid*)l, 16, 0, 0);
}

// ---------- kernel 1: f32 -> bf16 (hi only)
__global__ void k_convert_hi(const float* __restrict__ src, ushort_t* __restrict__ hi, long n4) {
  long i = (long)blockIdx.x * blockDim.x + threadIdx.x;
  long stride = (long)gridDim.x * blockDim.x;
  for (; i < n4; i += stride) {
    float4 v = ((const float4*)src)[i];
    ushort4 h;
    h.x = f2bf(v.x); h.y = f2bf(v.y); h.z = f2bf(v.z); h.w = f2bf(v.w);
    ((ushort4*)hi)[i] = h;
  }
}

// ---------- kernel 1b: precompute bias[h][rr][cc] = table[rel_idx[rr,cc]*16+h]
__global__ void k_bias(const float* __restrict__ table, const int* __restrict__ rel_idx,
                       float* __restrict__ bias) {
  int i = blockIdx.x * 256 + threadIdx.x;   // 65536 total
  int h = i >> 12, rc = i & 4095;
  bias[i] = table[rel_idx[rc] * 16 + h];
}

// ---------- kernel 2: QKV GEMM, plain bf16, single-buffered loop (32 KiB) +
// LDS-staged coalesced epilogue (pitch-136 tile, transposed for V).
// LDS total 34,816 B -> 4 blocks/CU. Fragment-linear loop LDS (0 conflicts).
__global__ __launch_bounds__(256) void k_gemm_qkv(
    const ushort_t* __restrict__ xh, const ushort_t* __restrict__ wh,
    ushort_t* __restrict__ qh, ushort_t* __restrict__ kh, ushort_t* __restrict__ vt) {
  __shared__ __align__(16) ushort_t lds0[17408];  // loop: [0,16384); epi tile: 128x136
  const int tid = threadIdx.x, w = tid >> 6, lane = tid & 63;
  const int g = lane >> 4, l15 = lane & 15;
  // bijective XCD swizzle: nwg = 9408 = 8*1176
  int flat = blockIdx.x;
  int swz = (flat & 7) * 1176 + (flat >> 3);
  int bx = swz % 12, by = swz / 12;
  const int wm = w >> 1, wn = w & 1;

  f32x4 acc[4][4];
  #pragma unroll
  for (int r = 0; r < 4; r++)
    #pragma unroll
    for (int c = 0; c < 4; c++) acc[r][c] = (f32x4){0.f,0.f,0.f,0.f};

  // staging: 32 subtile-issues (A:16, B:16), 8 per wave.
  const ushort_t* sptr[8]; int loff[8];
  #pragma unroll
  for (int q = 0; q < 8; q++) {
    int gq = w*8 + q;
    int buf = gq >> 4, ti = gq & 15, s = ti >> 1, u = ti & 1;
    const ushort_t* src = buf ? wh : xh;
    size_t rb = buf ? (size_t)bx*128 : (size_t)by*128;
    sptr[q] = src + (rb + (size_t)(s*16 + l15))*512 + u*32 + g*8;
    loff[q] = buf*8192 + ti*512;
  }

  for (int kk = 0; kk < 512; kk += 64) {
    #pragma unroll
    for (int q = 0; q < 8; q++) gl_lds16(sptr[q] + kk, lds0 + loff[q]);
    __syncthreads();
    #pragma unroll
    for (int u = 0; u < 2; u++) {
      s16x8 af[4], bf[4];
      #pragma unroll
      for (int t = 0; t < 4; t++) {
        af[t] = *(const s16x8*)&lds0[((wm*4 + t)*2 + u)*512 + lane*8];
        bf[t] = *(const s16x8*)&lds0[8192 + ((wn*4 + t)*2 + u)*512 + lane*8];
      }
      #pragma unroll
      for (int r = 0; r < 4; r++)
        #pragma unroll
        for (int c = 0; c < 4; c++)
          acc[r][c] = __builtin_amdgcn_mfma_f32_16x16x32_bf16(af[r], bf[c], acc[r][c], 0, 0, 0);
    }
    __syncthreads();
  }

  // ---- epilogue: stage to LDS (pitch 136), then coalesced 16B stores.
  // bx 0-3 -> q, 4-7 -> k, 8-11 -> v(transposed).
  const int sel = bx >> 2;
  const int P = 136;
  if (sel < 2) {
    #pragma unroll
    for (int r = 0; r < 4; r++)
      #pragma unroll
      for (int c = 0; c < 4; c++)
        #pragma unroll
        for (int j = 0; j < 4; j++)
          lds0[(wm*64 + r*16 + g*4 + j)*P + wn*64 + c*16 + l15] = f2bf(acc[r][c][j]);
  } else {
    #pragma unroll
    for (int r = 0; r < 4; r++)
      #pragma unroll
      for (int c = 0; c < 4; c++)
        #pragma unroll
        for (int j = 0; j < 4; j++)
          lds0[(wn*64 + c*16 + l15)*P + wm*64 + r*16 + g*4 + j] = f2bf(acc[r][c][j]);
  }
  __syncthreads();
  ushort_t* dst = (sel == 0) ? qh : (sel == 1) ? kh : vt;
  #pragma unroll
  for (int p = 0; p < 8; p++) {
    int ch = p*256 + tid;              // 0..2047, 8-ushort chunks
    int region = ch >> 8;              // (bi,hi): 2048-ushort contiguous dst region
    int inner = ch & 255;
    int bi = region >> 2, hi = region & 3;
    s16x8 val;
    if (sel < 2) val = *(const s16x8*)&lds0[(bi*64 + (inner >> 2))*P + hi*32 + (inner & 3)*8];
    else         val = *(const s16x8*)&lds0[(hi*32 + (inner >> 3))*P + bi*64 + (inner & 7)*8];
    int b = by*2 + bi, h = (bx & 3)*4 + hi;
    *(s16x8*)&dst[(size_t)(b*16 + h)*2048 + inner*8] = val;
  }
}

// ---------- kernel 3: per-(b,h) attention, plain bf16, one wave per head-window.
__global__ __launch_bounds__(256) void k_attn(
    const ushort_t* __restrict__ qh, const ushort_t* __restrict__ kh,
    const ushort_t* __restrict__ vt, const float* __restrict__ bias,
    ushort_t* __restrict__ aoh) {
  __shared__ ushort_t plds[4][64*72];
  const int tid = threadIdx.x, w = tid >> 6, lane = tid & 63;
  const int g = lane >> 4, l15 = lane & 15;
  const int gw = blockIdx.x * 4 + w;      // 0 .. 25087
  const int b = gw >> 4, h = gw & 15;
  const size_t base = (size_t)(b*16 + h) * 2048;

  s16x8 qf[4], kf[4];
  #pragma unroll
  for (int t = 0; t < 4; t++) {
    size_t o = base + (size_t)(t*16 + l15)*32 + g*8;
    qf[t] = *(const s16x8*)&qh[o];
    kf[t] = *(const s16x8*)&kh[o];
  }
  s16x8 vf[2][2];
  #pragma unroll
  for (int kt = 0; kt < 2; kt++)
    #pragma unroll
    for (int nt = 0; nt < 2; nt++)
      vf[kt][nt] = *(const s16x8*)&vt[base + (size_t)(nt*16 + l15)*64 + kt*32 + g*8];

  f32x4 s[4][4];
  #pragma unroll
  for (int r = 0; r < 4; r++)
    #pragma unroll
    for (int c = 0; c < 4; c++) s[r][c] = (f32x4){0.f,0.f,0.f,0.f};
  #pragma unroll
  for (int r = 0; r < 4; r++)
    #pragma unroll
    for (int c = 0; c < 4; c++)
      s[r][c] = __builtin_amdgcn_mfma_f32_16x16x32_bf16(qf[r], kf[c], s[r][c], 0, 0, 0);

  const float invs = 0.17677669529663687f;  // 1/sqrt(32)
  const float* bh_ = bias + ((size_t)h << 12);
  #pragma unroll
  for (int r = 0; r < 4; r++)
    #pragma unroll
    for (int c = 0; c < 4; c++)
      #pragma unroll
      for (int j = 0; j < 4; j++) {
        int rr = r*16 + g*4 + j, cc = c*16 + l15;
        s[r][c][j] = s[r][c][j]*invs + bh_[rr*64 + cc];
      }

  #pragma unroll
  for (int r = 0; r < 4; r++)
    #pragma unroll
    for (int j = 0; j < 4; j++) {
      float mx = fmaxf(fmaxf(s[r][0][j], s[r][1][j]), fmaxf(s[r][2][j], s[r][3][j]));
      mx = fmaxf(mx, __shfl_xor(mx, 1));
      mx = fmaxf(mx, __shfl_xor(mx, 2));
      mx = fmaxf(mx, __shfl_xor(mx, 4));
      mx = fmaxf(mx, __shfl_xor(mx, 8));
      float p0 = __expf(s[r][0][j]-mx), p1 = __expf(s[r][1][j]-mx);
      float p2 = __expf(s[r][2][j]-mx), p3 = __expf(s[r][3][j]-mx);
      float sum = p0 + p1 + p2 + p3;
      sum += __shfl_xor(sum, 1);
      sum += __shfl_xor(sum, 2);
      sum += __shfl_xor(sum, 4);
      sum += __shfl_xor(sum, 8);
      float rv = 1.0f / sum;
      s[r][0][j] = p0*rv; s[r][1][j] = p1*rv; s[r][2][j] = p2*rv; s[r][3][j] = p3*rv;
    }

  ushort_t* Pm = plds[w];
  #pragma unroll
  for (int r = 0; r < 4; r++)
    #pragma unroll
    for (int c = 0; c < 4; c++)
      #pragma unroll
      for (int j = 0; j < 4; j++) {
        int rr = r*16 + g*4 + j, cc = c*16 + l15;
        Pm[rr*72 + cc] = f2bf(s[r][c][j]);
      }
  s16x8 pf[4][2];
  #pragma unroll
  for (int ta = 0; ta < 4; ta++)
    #pragma unroll
    for (int kt = 0; kt < 2; kt++)
      pf[ta][kt] = *(const s16x8*)&Pm[(ta*16 + l15)*72 + kt*32 + g*8];

  f32x4 o[4][2];
  #pragma unroll
  for (int ta = 0; ta < 4; ta++)
    #pragma unroll
    for (int nt = 0; nt < 2; nt++) o[ta][nt] = (f32x4){0.f,0.f,0.f,0.f};
  #pragma unroll
  for (int ta = 0; ta < 4; ta++)
    #pragma unroll
    for (int nt = 0; nt < 2; nt++)
      #pragma unroll
      for (int kt = 0; kt < 2; kt++)
        o[ta][nt] = __builtin_amdgcn_mfma_f32_16x16x32_bf16(pf[ta][kt], vf[kt][nt], o[ta][nt], 0, 0, 0);

  #pragma unroll
  for (int ta = 0; ta < 4; ta++)
    #pragma unroll
    for (int nt = 0; nt < 2; nt++)
      #pragma unroll
      for (int j = 0; j < 4; j++) {
        int rr = ta*16 + g*4 + j, dd = nt*16 + l15;
        aoh[((size_t)b*64 + rr)*512 + h*32 + dd] = f2bf(o[ta][nt][j]);
      }
}

// ---------- kernel 4: proj GEMM, plain bf16, single-buffered loop +
// LDS-staged f32 epilogue (two 64-row halves, pitch 132), + bias, f32 out.
__global__ __launch_bounds__(256) void k_gemm_proj(
    const ushort_t* __restrict__ ah, const ushort_t* __restrict__ wh,
    const float* __restrict__ pb, float* __restrict__ out) {
  __shared__ __align__(16) ushort_t lds0[16896];  // loop 32KB; epi: 64x132 f32 = 33,792B
  const int tid = threadIdx.x, w = tid >> 6, lane = tid & 63;
  const int g = lane >> 4, l15 = lane & 15;
  int flat = blockIdx.x;                    // nwg = 3136 = 8*392
  int swz = (flat & 7) * 392 + (flat >> 3);
  int bx = swz & 3, by = swz >> 2;
  const int wm = w >> 1, wn = w & 1;

  f32x4 acc[4][4];
  #pragma unroll
  for (int r = 0; r < 4; r++)
    #pragma unroll
    for (int c = 0; c < 4; c++) acc[r][c] = (f32x4){0.f,0.f,0.f,0.f};

  const ushort_t* sptr[8]; int loff[8];
  #pragma unroll
  for (int q = 0; q < 8; q++) {
    int gq = w*8 + q;
    int buf = gq >> 4, ti = gq & 15, s = ti >> 1, u = ti & 1;
    const ushort_t* src = buf ? wh : ah;
    size_t rb = buf ? (size_t)bx*128 : (size_t)by*128;
    sptr[q] = src + (rb + (size_t)(s*16 + l15))*512 + u*32 + g*8;
    loff[q] = buf*8192 + ti*512;
  }

  for (int kk = 0; kk < 512; kk += 64) {
    #pragma unroll
    for (int q = 0; q < 8; q++) gl_lds16(sptr[q] + kk, lds0 + loff[q]);
    __syncthreads();
    #pragma unroll
    for (int u = 0; u < 2; u++) {
      s16x8 af[4], bf[4];
      #pragma unroll
      for (int t = 0; t < 4; t++) {
        af[t] = *(const s16x8*)&lds0[((wm*4 + t)*2 + u)*512 + lane*8];
        bf[t] = *(const s16x8*)&lds0[8192 + ((wn*4 + t)*2 + u)*512 + lane*8];
      }
      #pragma unroll
      for (int r = 0; r < 4; r++)
        #pragma unroll
        for (int c = 0; c < 4; c++)
          acc[r][c] = __builtin_amdgcn_mfma_f32_16x16x32_bf16(af[r], bf[c], acc[r][c], 0, 0, 0);
    }
    __syncthreads();
  }

  // ---- epilogue: two half-tiles (wm==half), f32 pitch-132 LDS, coalesced stores.
  float* Tf = (float*)lds0;
  const int PF = 132;
  #pragma unroll
  for (int half = 0; half < 2; half++) {
    if (wm == half) {
      #pragma unroll
      for (int r = 0; r < 4; r++)
        #pragma unroll
        for (int c = 0; c < 4; c++)
          #pragma unroll
          for (int j = 0; j < 4; j++)
            Tf[(r*16 + g*4 + j)*PF + wn*64 + c*16 + l15] = acc[r][c][j];
    }
    __syncthreads();
    #pragma unroll
    for (int p = 0; p < 8; p++) {
      int ch = p*256 + tid;       // 0..2047 chunks of 4 f32
      int row = ch >> 5, c4 = ch & 31;
      f32x4 v = *(const f32x4*)&Tf[row*PF + c4*4];
      int ncol = bx*128 + c4*4;
      f32x4 pbv = *(const f32x4*)&pb[ncol];
      v = v + pbv;
      *(f32x4*)&out[(size_t)(by*128 + half*64 + row)*512 + ncol] = v;
    }
    __syncthreads();
  }
}

extern "C" void kernel_launch(void* const* d_in, const int* in_sizes, int n_in,
                              void* d_out, int out_size, void* d_ws, size_t ws_size,
                              hipStream_t stream) {
  const float* x      = (const float*)d_in[0];
  const float* qkv_w  = (const float*)d_in[1];
  const float* table  = (const float*)d_in[2];
  const float* proj_w = (const float*)d_in[3];
  const float* proj_b = (const float*)d_in[4];
  const int*   rel_idx = (const int*)d_in[5];

  const size_t S1 = S1_ELEMS;
  const size_t need = (4*S1 + 786432 + 262144)*sizeof(ushort_t) + 65536*sizeof(float);
  if (ws_size < need) return;

  ushort_t* qh  = (ushort_t*)d_ws;
  ushort_t* kh  = qh + S1;
  ushort_t* vt  = kh + S1;
  ushort_t* xh  = vt + S1;        // reused as attention-out after QKV GEMM
  ushort_t* wqh = xh + S1;
  ushort_t* wph = wqh + 786432;
  float*    bias = (float*)(wph + 262144);
  ushort_t* aoh = xh;

  k_convert_hi<<<2048, 256, 0, stream>>>(x, xh, (long)(S1/4));
  k_convert_hi<<<768, 256, 0, stream>>>(qkv_w, wqh, 196608);
  k_convert_hi<<<256, 256, 0, stream>>>(proj_w, wph, 65536);
  k_bias<<<256, 256, 0, stream>>>(table, rel_idx, bias);
  k_gemm_qkv<<<9408, 256, 0, stream>>>(xh, wqh, qh, kh, vt);
  k_attn<<<6272, 256, 0, stream>>>(qh, kh, vt, bias, aoh);
  k_gemm_proj<<<3136, 256, 0, stream>>>(aoh, wph, proj_b, (float*)d_out);
}

// Round 5
// 591.882 us; speedup vs baseline: 1.3089x; 1.1258x over previous
//
#include <hip/hip_runtime.h>
#include <stdint.h>

typedef unsigned short ushort_t;
typedef __attribute__((ext_vector_type(4))) float f32x4;
typedef __attribute__((ext_vector_type(8))) short s16x8;

#define S1_ELEMS ((size_t)1568*64*512)   // 51,380,224 elements per q/k/v/x/ao buffer

// ---------- bf16 helpers (RNE)
__device__ __forceinline__ ushort_t f2bf(float f) {
  unsigned u = __builtin_bit_cast(unsigned, f);
  u = u + 0x7fffu + ((u >> 16) & 1u);
  return (ushort_t)(u >> 16);
}

// ---------- async global->LDS, 16B per lane (dest = uniform base + lane*16)
__device__ __forceinline__ void gl_lds16(const ushort_t* g, ushort_t* l) {
  typedef __attribute__((address_space(1))) void gvoid;
  typedef __attribute__((address_space(3))) void lvoid;
  __builtin_amdgcn_global_load_lds((gvoid*)(ushort_t*)g, (lvoid*)l, 16, 0, 0);
}

// ---------- kernel 1: f32 -> bf16 (hi only)
__global__ void k_convert_hi(const float* __restrict__ src, ushort_t* __restrict__ hi, long n4) {
  long i = (long)blockIdx.x * blockDim.x + threadIdx.x;
  long stride = (long)gridDim.x * blockDim.x;
  for (; i < n4; i += stride) {
    float4 v = ((const float4*)src)[i];
    ushort4 h;
    h.x = f2bf(v.x); h.y = f2bf(v.y); h.z = f2bf(v.z); h.w = f2bf(v.w);
    ((ushort4*)hi)[i] = h;
  }
}

// ---------- kernel 1b: precompute bias[h][rr][cc] = table[rel_idx[rr,cc]*16+h]
__global__ void k_bias(const float* __restrict__ table, const int* __restrict__ rel_idx,
                       float* __restrict__ bias) {
  int i = blockIdx.x * 256 + threadIdx.x;   // 65536 total
  int h = i >> 12, rc = i & 4095;
  bias[i] = table[rel_idx[rc] * 16 + h];
}

// ================= QKV GEMM: 256x256 tile, 8 waves (2x4), BK=64, 8 K-tiles.
// 4 phases per K-tile (kh,rh quadrants), 1 half-tile staged per phase,
// counted vmcnt(8) twice per K-tile, raw s_barrier, setprio around MFMA.
// LDS: 2 bufs x (A 256x64 | B 256x64) bf16 = 131072 B (dynamic), fragment-linear.
struct GemmCtx {
  ushort_t* lds;
  const ushort_t *pA0, *pA1, *pB0, *pB1;
  int w, lane, wm, wn;
};

template<int BUFP, int KH, int RH, int SSEL, int SBUFP, int SU, int VM>
__device__ __forceinline__ void phase(const GemmCtx& C, f32x4 (&acc)[8][4], s16x8 (&bf)[4], int stau) {
  s16x8 af[4];
  #pragma unroll
  for (int t = 0; t < 4; t++)
    af[t] = *(const s16x8*)&C.lds[BUFP*32768 + ((C.wm*8 + RH*4 + t)*2 + KH)*512 + C.lane*8];
  if constexpr (RH == 0) {
    #pragma unroll
    for (int t = 0; t < 4; t++)
      bf[t] = *(const s16x8*)&C.lds[BUFP*32768 + 16384 + ((C.wn*4 + t)*2 + KH)*512 + C.lane*8];
  }
  if constexpr (SSEL == 0) {
    gl_lds16(C.pA0 + stau*64 + SU*32, C.lds + SBUFP*32768 + (4*C.w + SU)*512);
    gl_lds16(C.pA1 + stau*64 + SU*32, C.lds + SBUFP*32768 + (4*C.w + 2 + SU)*512);
  } else if constexpr (SSEL == 1) {
    gl_lds16(C.pB0 + stau*64 + SU*32, C.lds + SBUFP*32768 + 16384 + (4*C.w + SU)*512);
    gl_lds16(C.pB1 + stau*64 + SU*32, C.lds + SBUFP*32768 + 16384 + (4*C.w + 2 + SU)*512);
  }
  if constexpr (VM == 8) asm volatile("s_waitcnt vmcnt(8)" ::: "memory");
  else if constexpr (VM == 4) asm volatile("s_waitcnt vmcnt(4)" ::: "memory");
  else if constexpr (VM == 0) asm volatile("s_waitcnt vmcnt(0)" ::: "memory");
  __builtin_amdgcn_s_barrier();
  __builtin_amdgcn_s_setprio(1);
  #pragma unroll
  for (int ta = 0; ta < 4; ta++)
    #pragma unroll
    for (int tb = 0; tb < 4; tb++)
      acc[RH*4 + ta][tb] = __builtin_amdgcn_mfma_f32_16x16x32_bf16(af[ta], bf[tb], acc[RH*4 + ta][tb], 0, 0, 0);
  __builtin_amdgcn_s_setprio(0);
  __builtin_amdgcn_s_barrier();
}

// per K-tile tau: q1 stages A-kh1(tau+1), q2 B-kh1(tau+1) [vmcnt],
//                 q3 stages A-kh0(tau+2), q4 B-kh0(tau+2) [vmcnt]
template<int BUFP, bool S12, bool S34, int VM2, int VM4>
__device__ __forceinline__ void ktile(const GemmCtx& C, f32x4 (&acc)[8][4], int tau) {
  s16x8 bf[4];
  phase<BUFP, 0, 0, S12 ? 0 : -1, BUFP^1, 1, -1 >(C, acc, bf, tau + 1);
  phase<BUFP, 0, 1, S12 ? 1 : -1, BUFP^1, 1, VM2>(C, acc, bf, tau + 1);
  phase<BUFP, 1, 0, S34 ? 0 : -1, BUFP,   0, -1 >(C, acc, bf, tau + 2);
  phase<BUFP, 1, 1, S34 ? 1 : -1, BUFP,   0, VM4>(C, acc, bf, tau + 2);
}

__global__ __launch_bounds__(512, 2) void k_gemm_qkv(
    const ushort_t* __restrict__ xh, const ushort_t* __restrict__ wh,
    ushort_t* __restrict__ qh, ushort_t* __restrict__ kh, ushort_t* __restrict__ vt) {
  extern __shared__ __align__(16) ushort_t lds[];
  const int tid = threadIdx.x, w = tid >> 6, lane = tid & 63;
  const int g = lane >> 4, l15 = lane & 15;
  const int wm = w >> 2, wn = w & 3;
  int flat = blockIdx.x;                 // 2352 = 8*294, bijective XCD swizzle
  int swz = (flat & 7) * 294 + (flat >> 3);
  int bx = swz % 6, by = swz / 6;        // bx fastest -> same-A blocks adjacent per XCD

  GemmCtx C;
  C.lds = lds;
  C.pA0 = xh + ((size_t)by*256 + (size_t)(2*w)*16 + l15)*512 + g*8;
  C.pA1 = C.pA0 + 16*512;
  C.pB0 = wh + ((size_t)bx*256 + (size_t)(2*w)*16 + l15)*512 + g*8;
  C.pB1 = C.pB0 + 16*512;
  C.w = w; C.lane = lane; C.wm = wm; C.wn = wn;

  f32x4 acc[8][4];
  #pragma unroll
  for (int r = 0; r < 8; r++)
    #pragma unroll
    for (int c = 0; c < 4; c++) acc[r][c] = (f32x4){0.f, 0.f, 0.f, 0.f};

  // prologue: A0(0),B0(0),A1(0),B1(0),A0(1),B0(1); keep last 2 halves in flight
  gl_lds16(C.pA0 +  0, lds + (4*w + 0)*512);
  gl_lds16(C.pA1 +  0, lds + (4*w + 2)*512);
  gl_lds16(C.pB0 +  0, lds + 16384 + (4*w + 0)*512);
  gl_lds16(C.pB1 +  0, lds + 16384 + (4*w + 2)*512);
  gl_lds16(C.pA0 + 32, lds + (4*w + 1)*512);
  gl_lds16(C.pA1 + 32, lds + (4*w + 3)*512);
  gl_lds16(C.pB0 + 32, lds + 16384 + (4*w + 1)*512);
  gl_lds16(C.pB1 + 32, lds + 16384 + (4*w + 3)*512);
  gl_lds16(C.pA0 + 64, lds + 32768 + (4*w + 0)*512);
  gl_lds16(C.pA1 + 64, lds + 32768 + (4*w + 2)*512);
  gl_lds16(C.pB0 + 64, lds + 32768 + 16384 + (4*w + 0)*512);
  gl_lds16(C.pB1 + 64, lds + 32768 + 16384 + (4*w + 2)*512);
  asm volatile("s_waitcnt vmcnt(4)" ::: "memory");
  __builtin_amdgcn_s_barrier();

  for (int kt = 0; kt < 6; kt += 2) {
    ktile<0, true, true, 8, 8>(C, acc, kt);
    ktile<1, true, true, 8, 8>(C, acc, kt + 1);
  }
  ktile<0, true,  false, 8, 4>(C, acc, 6);   // tail: vmcnt(4) guards tile7 kh0
  ktile<1, false, false, 0, -1>(C, acc, 7);  // tail: vmcnt(0) guards tile7 kh1

  asm volatile("" ::: "memory");  // keep epilogue LDS writes below the last barrier

  // ---- epilogue: acc -> LDS in destination-region order, then coalesced stores.
  // bx: 0,1 -> q ; 2,3 -> k ; 4,5 -> v (transposed d-major regions)
  const int sel = bx >> 1;
  #pragma unroll
  for (int ra = 0; ra < 8; ra++)
    #pragma unroll
    for (int tb = 0; tb < 4; tb++)
      #pragma unroll
      for (int j = 0; j < 4; j++) {
        int row = wm*128 + ra*16 + g*4 + j;
        int col = wn*64 + tb*16 + l15;
        int b_i = row >> 6, n = row & 63, h_i = col >> 5, d = col & 31;
        int addr = (sel == 2) ? ((b_i*8 + h_i)*2048 + d*64 + n)
                              : ((b_i*8 + h_i)*2048 + n*32 + d);
        lds[addr] = f2bf(acc[ra][tb][j]);
      }
  asm volatile("s_waitcnt lgkmcnt(0)" ::: "memory");
  __builtin_amdgcn_s_barrier();
  ushort_t* dst = (sel == 0) ? qh : (sel == 1) ? kh : vt;
  const int hbase = (bx & 1) * 8;
  #pragma unroll
  for (int it = 0; it < 16; it++) {
    int cg = it*512 + tid;
    int region = cg >> 8, inner = cg & 255;
    int b_i = region >> 3, h_i = region & 7;
    s16x8 v = *(const s16x8*)&lds[region*2048 + inner*8];
    int b = by*4 + b_i, h = hbase + h_i;
    *(s16x8*)&dst[(size_t)(b*16 + h)*2048 + inner*8] = v;
  }
}

// ---------- kernel 3: per-(b,h) attention, plain bf16, one wave per head-window.
__global__ __launch_bounds__(256) void k_attn(
    const ushort_t* __restrict__ qh, const ushort_t* __restrict__ kh,
    const ushort_t* __restrict__ vt, const float* __restrict__ bias,
    ushort_t* __restrict__ aoh) {
  __shared__ ushort_t plds[4][64*72];
  const int tid = threadIdx.x, w = tid >> 6, lane = tid & 63;
  const int g = lane >> 4, l15 = lane & 15;
  const int gw = blockIdx.x * 4 + w;      // 0 .. 25087
  const int b = gw >> 4, h = gw & 15;
  const size_t base = (size_t)(b*16 + h) * 2048;

  s16x8 qf[4], kf[4];
  #pragma unroll
  for (int t = 0; t < 4; t++) {
    size_t o = base + (size_t)(t*16 + l15)*32 + g*8;
    qf[t] = *(const s16x8*)&qh[o];
    kf[t] = *(const s16x8*)&kh[o];
  }
  s16x8 vf[2][2];
  #pragma unroll
  for (int kt = 0; kt < 2; kt++)
    #pragma unroll
    for (int nt = 0; nt < 2; nt++)
      vf[kt][nt] = *(const s16x8*)&vt[base + (size_t)(nt*16 + l15)*64 + kt*32 + g*8];

  f32x4 s[4][4];
  #pragma unroll
  for (int r = 0; r < 4; r++)
    #pragma unroll
    for (int c = 0; c < 4; c++) s[r][c] = (f32x4){0.f,0.f,0.f,0.f};
  #pragma unroll
  for (int r = 0; r < 4; r++)
    #pragma unroll
    for (int c = 0; c < 4; c++)
      s[r][c] = __builtin_amdgcn_mfma_f32_16x16x32_bf16(qf[r], kf[c], s[r][c], 0, 0, 0);

  const float invs = 0.17677669529663687f;  // 1/sqrt(32)
  const float* bh_ = bias + ((size_t)h << 12);
  #pragma unroll
  for (int r = 0; r < 4; r++)
    #pragma unroll
    for (int c = 0; c < 4; c++)
      #pragma unroll
      for (int j = 0; j < 4; j++) {
        int rr = r*16 + g*4 + j, cc = c*16 + l15;
        s[r][c][j] = s[r][c][j]*invs + bh_[rr*64 + cc];
      }

  #pragma unroll
  for (int r = 0; r < 4; r++)
    #pragma unroll
    for (int j = 0; j < 4; j++) {
      float mx = fmaxf(fmaxf(s[r][0][j], s[r][1][j]), fmaxf(s[r][2][j], s[r][3][j]));
      mx = fmaxf(mx, __shfl_xor(mx, 1));
      mx = fmaxf(mx, __shfl_xor(mx, 2));
      mx = fmaxf(mx, __shfl_xor(mx, 4));
      mx = fmaxf(mx, __shfl_xor(mx, 8));
      float p0 = __expf(s[r][0][j]-mx), p1 = __expf(s[r][1][j]-mx);
      float p2 = __expf(s[r][2][j]-mx), p3 = __expf(s[r][3][j]-mx);
      float sum = p0 + p1 + p2 + p3;
      sum += __shfl_xor(sum, 1);
      sum += __shfl_xor(sum, 2);
      sum += __shfl_xor(sum, 4);
      sum += __shfl_xor(sum, 8);
      float rv = 1.0f / sum;
      s[r][0][j] = p0*rv; s[r][1][j] = p1*rv; s[r][2][j] = p2*rv; s[r][3][j] = p3*rv;
    }

  ushort_t* Pm = plds[w];
  #pragma unroll
  for (int r = 0; r < 4; r++)
    #pragma unroll
    for (int c = 0; c < 4; c++)
      #pragma unroll
      for (int j = 0; j < 4; j++) {
        int rr = r*16 + g*4 + j, cc = c*16 + l15;
        Pm[rr*72 + cc] = f2bf(s[r][c][j]);
      }
  s16x8 pf[4][2];
  #pragma unroll
  for (int ta = 0; ta < 4; ta++)
    #pragma unroll
    for (int kt = 0; kt < 2; kt++)
      pf[ta][kt] = *(const s16x8*)&Pm[(ta*16 + l15)*72 + kt*32 + g*8];

  f32x4 o[4][2];
  #pragma unroll
  for (int ta = 0; ta < 4; ta++)
    #pragma unroll
    for (int nt = 0; nt < 2; nt++) o[ta][nt] = (f32x4){0.f,0.f,0.f,0.f};
  #pragma unroll
  for (int ta = 0; ta < 4; ta++)
    #pragma unroll
    for (int nt = 0; nt < 2; nt++)
      #pragma unroll
      for (int kt = 0; kt < 2; kt++)
        o[ta][nt] = __builtin_amdgcn_mfma_f32_16x16x32_bf16(pf[ta][kt], vf[kt][nt], o[ta][nt], 0, 0, 0);

  #pragma unroll
  for (int ta = 0; ta < 4; ta++)
    #pragma unroll
    for (int nt = 0; nt < 2; nt++)
      #pragma unroll
      for (int j = 0; j < 4; j++) {
        int rr = ta*16 + g*4 + j, dd = nt*16 + l15;
        aoh[((size_t)b*64 + rr)*512 + h*32 + dd] = f2bf(o[ta][nt][j]);
      }
}

// ---------- kernel 4: proj GEMM, plain bf16, single-buffered loop +
// LDS-staged f32 epilogue (two 64-row halves, pitch 132), + bias, f32 out.
__global__ __launch_bounds__(256) void k_gemm_proj(
    const ushort_t* __restrict__ ah, const ushort_t* __restrict__ wh,
    const float* __restrict__ pb, float* __restrict__ out) {
  __shared__ __align__(16) ushort_t lds0[16896];
  const int tid = threadIdx.x, w = tid >> 6, lane = tid & 63;
  const int g = lane >> 4, l15 = lane & 15;
  int flat = blockIdx.x;                    // nwg = 3136 = 8*392
  int swz = (flat & 7) * 392 + (flat >> 3);
  int bx = swz & 3, by = swz >> 2;
  const int wm = w >> 1, wn = w & 1;

  f32x4 acc[4][4];
  #pragma unroll
  for (int r = 0; r < 4; r++)
    #pragma unroll
    for (int c = 0; c < 4; c++) acc[r][c] = (f32x4){0.f,0.f,0.f,0.f};

  const ushort_t* sptr[8]; int loff[8];
  #pragma unroll
  for (int q = 0; q < 8; q++) {
    int gq = w*8 + q;
    int buf = gq >> 4, ti = gq & 15, s = ti >> 1, u = ti & 1;
    const ushort_t* src = buf ? wh : ah;
    size_t rb = buf ? (size_t)bx*128 : (size_t)by*128;
    sptr[q] = src + (rb + (size_t)(s*16 + l15))*512 + u*32 + g*8;
    loff[q] = buf*8192 + ti*512;
  }

  for (int kk = 0; kk < 512; kk += 64) {
    #pragma unroll
    for (int q = 0; q < 8; q++) gl_lds16(sptr[q] + kk, lds0 + loff[q]);
    __syncthreads();
    #pragma unroll
    for (int u = 0; u < 2; u++) {
      s16x8 af[4], bf[4];
      #pragma unroll
      for (int t = 0; t < 4; t++) {
        af[t] = *(const s16x8*)&lds0[((wm*4 + t)*2 + u)*512 + lane*8];
        bf[t] = *(const s16x8*)&lds0[8192 + ((wn*4 + t)*2 + u)*512 + lane*8];
      }
      #pragma unroll
      for (int r = 0; r < 4; r++)
        #pragma unroll
        for (int c = 0; c < 4; c++)
          acc[r][c] = __builtin_amdgcn_mfma_f32_16x16x32_bf16(af[r], bf[c], acc[r][c], 0, 0, 0);
    }
    __syncthreads();
  }

  float* Tf = (float*)lds0;
  const int PF = 132;
  #pragma unroll
  for (int half = 0; half < 2; half++) {
    if (wm == half) {
      #pragma unroll
      for (int r = 0; r < 4; r++)
        #pragma unroll
        for (int c = 0; c < 4; c++)
          #pragma unroll
          for (int j = 0; j < 4; j++)
            Tf[(r*16 + g*4 + j)*PF + wn*64 + c*16 + l15] = acc[r][c][j];
    }
    __syncthreads();
    #pragma unroll
    for (int p = 0; p < 8; p++) {
      int ch = p*256 + tid;
      int row = ch >> 5, c4 = ch & 31;
      f32x4 v = *(const f32x4*)&Tf[row*PF + c4*4];
      int ncol = bx*128 + c4*4;
      f32x4 pbv = *(const f32x4*)&pb[ncol];
      v = v + pbv;
      *(f32x4*)&out[(size_t)(by*128 + half*64 + row)*512 + ncol] = v;
    }
    __syncthreads();
  }
}

extern "C" void kernel_launch(void* const* d_in, const int* in_sizes, int n_in,
                              void* d_out, int out_size, void* d_ws, size_t ws_size,
                              hipStream_t stream) {
  const float* x      = (const float*)d_in[0];
  const float* qkv_w  = (const float*)d_in[1];
  const float* table  = (const float*)d_in[2];
  const float* proj_w = (const float*)d_in[3];
  const float* proj_b = (const float*)d_in[4];
  const int*   rel_idx = (const int*)d_in[5];

  const size_t S1 = S1_ELEMS;
  const size_t need = (4*S1 + 786432 + 262144)*sizeof(ushort_t) + 65536*sizeof(float);
  if (ws_size < need) return;

  ushort_t* qh  = (ushort_t*)d_ws;
  ushort_t* kh  = qh + S1;
  ushort_t* vt  = kh + S1;
  ushort_t* xh  = vt + S1;        // reused as attention-out after QKV GEMM
  ushort_t* wqh = xh + S1;
  ushort_t* wph = wqh + 786432;
  float*    bias = (float*)(wph + 262144);
  ushort_t* aoh = xh;

  hipFuncSetAttribute((const void*)k_gemm_qkv,
                      hipFuncAttributeMaxDynamicSharedMemorySize, 131072);

  k_convert_hi<<<2048, 256, 0, stream>>>(x, xh, (long)(S1/4));
  k_convert_hi<<<768, 256, 0, stream>>>(qkv_w, wqh, 196608);
  k_convert_hi<<<256, 256, 0, stream>>>(proj_w, wph, 65536);
  k_bias<<<256, 256, 0, stream>>>(table, rel_idx, bias);
  k_gemm_qkv<<<2352, 512, 131072, stream>>>(xh, wqh, qh, kh, vt);
  k_attn<<<6272, 256, 0, stream>>>(qh, kh, vt, bias, aoh);
  k_gemm_proj<<<3136, 256, 0, stream>>>(aoh, wph, proj_b, (float*)d_out);
}

// Round 6
// 558.180 us; speedup vs baseline: 1.3879x; 1.0604x over previous
//
#include <hip/hip_runtime.h>
#include <stdint.h>

typedef unsigned short ushort_t;
typedef unsigned long long u64_t;
typedef __attribute__((ext_vector_type(4))) float f32x4;
typedef __attribute__((ext_vector_type(8))) short s16x8;

#define S1_ELEMS ((size_t)1568*64*512)   // 51,380,224 elements per q/k/v/x/ao buffer

// ---------- bf16 helpers (RNE)
__device__ __forceinline__ ushort_t f2bf(float f) {
  unsigned u = __builtin_bit_cast(unsigned, f);
  u = u + 0x7fffu + ((u >> 16) & 1u);
  return (ushort_t)(u >> 16);
}

// ---------- async global->LDS, 16B per lane (dest = uniform base + lane*16)
__device__ __forceinline__ void gl_lds16(const ushort_t* g, ushort_t* l) {
  typedef __attribute__((address_space(1))) void gvoid;
  typedef __attribute__((address_space(3))) void lvoid;
  __builtin_amdgcn_global_load_lds((gvoid*)(ushort_t*)g, (lvoid*)l, 16, 0, 0);
}

// ---------- kernel 1: f32 -> bf16 (hi only)
__global__ void k_convert_hi(const float* __restrict__ src, ushort_t* __restrict__ hi, long n4) {
  long i = (long)blockIdx.x * blockDim.x + threadIdx.x;
  long stride = (long)gridDim.x * blockDim.x;
  for (; i < n4; i += stride) {
    float4 v = ((const float4*)src)[i];
    ushort4 h;
    h.x = f2bf(v.x); h.y = f2bf(v.y); h.z = f2bf(v.z); h.w = f2bf(v.w);
    ((ushort4*)hi)[i] = h;
  }
}

// ---------- kernel 1b: precompute bias[h][rr][cc] = table[rel_idx[rr,cc]*16+h]
__global__ void k_bias(const float* __restrict__ table, const int* __restrict__ rel_idx,
                       float* __restrict__ bias) {
  int i = blockIdx.x * 256 + threadIdx.x;   // 65536 total
  int h = i >> 12, rc = i & 4095;
  bias[i] = table[rel_idx[rc] * 16 + h];
}

// ================= shared 256x256 BK=64 loop (8 waves 2x4, fragment-linear LDS,
// 2 MFMA bursts of 32 per K-tile, 2 barriers/tile, 1-tile stage lead, vmcnt(0) at tile end).
// LDS: 2 bufs x (A 256x64 | B 256x64) bf16 = 131072 B dynamic.
__device__ __forceinline__ void gemm256_loop(
    ushort_t* lds, const ushort_t* pA, const ushort_t* pB,
    int w, int lane, int wm, int wn, f32x4 (&acc)[8][4]) {
  // prologue: stage tile 0 into buf 0
  #pragma unroll
  for (int q = 0; q < 2; q++) {
    gl_lds16(pA + q*8192 +  0, lds + ((2*w + q)*2 + 0)*512);
    gl_lds16(pA + q*8192 + 32, lds + ((2*w + q)*2 + 1)*512);
    gl_lds16(pB + q*8192 +  0, lds + 16384 + ((2*w + q)*2 + 0)*512);
    gl_lds16(pB + q*8192 + 32, lds + 16384 + ((2*w + q)*2 + 1)*512);
  }
  asm volatile("s_waitcnt vmcnt(0)" ::: "memory");
  __builtin_amdgcn_s_barrier();

  for (int tau = 0; tau < 8; ++tau) {
    ushort_t* bufR = lds + (tau & 1)*32768;
    ushort_t* bufW = lds + ((tau & 1) ^ 1)*32768;
    if (tau < 7) {                    // stage tile tau+1 (1-tile lead)
      int ko = (tau + 1)*64;
      #pragma unroll
      for (int q = 0; q < 2; q++) {
        gl_lds16(pA + q*8192 + ko,      bufW + ((2*w + q)*2 + 0)*512);
        gl_lds16(pA + q*8192 + ko + 32, bufW + ((2*w + q)*2 + 1)*512);
        gl_lds16(pB + q*8192 + ko,      bufW + 16384 + ((2*w + q)*2 + 0)*512);
        gl_lds16(pB + q*8192 + ko + 32, bufW + 16384 + ((2*w + q)*2 + 1)*512);
      }
    }
    s16x8 af[4][2], bf[4][2];
    #pragma unroll
    for (int t = 0; t < 4; t++)
      #pragma unroll
      for (int kh = 0; kh < 2; kh++) {
        af[t][kh] = *(const s16x8*)&bufR[((wm*8 + t)*2 + kh)*512 + lane*8];
        bf[t][kh] = *(const s16x8*)&bufR[16384 + ((wn*4 + t)*2 + kh)*512 + lane*8];
      }
    __builtin_amdgcn_s_barrier();
    asm volatile("s_waitcnt lgkmcnt(0)" ::: "memory");
    __builtin_amdgcn_sched_barrier(0);
    __builtin_amdgcn_s_setprio(1);
    #pragma unroll
    for (int t = 0; t < 4; t++)
      #pragma unroll
      for (int tb = 0; tb < 4; tb++) {
        acc[t][tb] = __builtin_amdgcn_mfma_f32_16x16x32_bf16(af[t][0], bf[tb][0], acc[t][tb], 0, 0, 0);
        acc[t][tb] = __builtin_amdgcn_mfma_f32_16x16x32_bf16(af[t][1], bf[tb][1], acc[t][tb], 0, 0, 0);
      }
    __builtin_amdgcn_s_setprio(0);
    s16x8 ag[4][2];
    #pragma unroll
    for (int t = 0; t < 4; t++)
      #pragma unroll
      for (int kh = 0; kh < 2; kh++)
        ag[t][kh] = *(const s16x8*)&bufR[((wm*8 + 4 + t)*2 + kh)*512 + lane*8];
    asm volatile("s_waitcnt lgkmcnt(0)" ::: "memory");
    __builtin_amdgcn_sched_barrier(0);
    __builtin_amdgcn_s_setprio(1);
    #pragma unroll
    for (int t = 0; t < 4; t++)
      #pragma unroll
      for (int tb = 0; tb < 4; tb++) {
        acc[4 + t][tb] = __builtin_amdgcn_mfma_f32_16x16x32_bf16(ag[t][0], bf[tb][0], acc[4 + t][tb], 0, 0, 0);
        acc[4 + t][tb] = __builtin_amdgcn_mfma_f32_16x16x32_bf16(ag[t][1], bf[tb][1], acc[4 + t][tb], 0, 0, 0);
      }
    __builtin_amdgcn_s_setprio(0);
    asm volatile("s_waitcnt vmcnt(0)" ::: "memory");
    __builtin_amdgcn_s_barrier();
  }
}

// ================= QKV GEMM: 256x256 tiles, conflict-free swizzled epilogue.
__global__ __launch_bounds__(512, 2) void k_gemm_qkv(
    const ushort_t* __restrict__ xh, const ushort_t* __restrict__ wh,
    ushort_t* __restrict__ qh, ushort_t* __restrict__ kh, ushort_t* __restrict__ vt) {
  extern __shared__ __align__(16) ushort_t lds[];
  const int tid = threadIdx.x, w = tid >> 6, lane = tid & 63;
  const int g = lane >> 4, l15 = lane & 15;
  const int wm = w >> 2, wn = w & 3;
  int flat = blockIdx.x;                 // 2352 = 8*294, bijective XCD swizzle
  int swz = (flat & 7) * 294 + (flat >> 3);
  int bx = swz % 6, by = swz / 6;

  const ushort_t* pA = xh + ((size_t)by*256 + (size_t)(2*w)*16 + l15)*512 + g*8;
  const ushort_t* pB = wh + ((size_t)bx*256 + (size_t)(2*w)*16 + l15)*512 + g*8;

  f32x4 acc[8][4];
  #pragma unroll
  for (int r = 0; r < 8; r++)
    #pragma unroll
    for (int c = 0; c < 4; c++) acc[r][c] = (f32x4){0.f, 0.f, 0.f, 0.f};

  gemm256_loop(lds, pA, pB, w, lane, wm, wn, acc);

  // ---- epilogue: acc -> LDS (swizzled, conflict-free), then coalesced stores.
  // 32 regions (b_i*8+h_i) x 2048 elems = 128 KiB. bx: 0,1->q  2,3->k  4,5->v(T)
  asm volatile("" ::: "memory");
  const int sel = bx >> 1;
  if (sel < 2) {
    #pragma unroll
    for (int ra = 0; ra < 8; ra++)
      #pragma unroll
      for (int tb = 0; tb < 4; tb++)
        #pragma unroll
        for (int j = 0; j < 4; j++) {
          int row = wm*128 + ra*16 + g*4 + j;
          int col = wn*64 + tb*16 + l15;
          int r = (row >> 6)*8 + (col >> 5);
          int n = row & 63, d = col & 31;
          int byte = r*4096 + ((n*64 + d*2) ^ ((n & 12) << 3));
          *(ushort_t*)((char*)lds + byte) = f2bf(acc[ra][tb][j]);
        }
  } else {
    #pragma unroll
    for (int ra = 0; ra < 8; ra++)
      #pragma unroll
      for (int tb = 0; tb < 4; tb++) {
        int row0 = wm*128 + ra*16 + g*4;
        int col = wn*64 + tb*16 + l15;
        int r = (row0 >> 6)*8 + (col >> 5);
        int n0 = row0 & 63, d = col & 31;
        u64_t pk = (u64_t)f2bf(acc[ra][tb][0])
                 | ((u64_t)f2bf(acc[ra][tb][1]) << 16)
                 | ((u64_t)f2bf(acc[ra][tb][2]) << 32)
                 | ((u64_t)f2bf(acc[ra][tb][3]) << 48);
        int byte = r*4096 + ((d*128 + n0*2) ^ ((d & 7) << 4) ^ (((((d >> 3) ^ (n0 >> 3))) & 1) << 6));
        *(u64_t*)((char*)lds + byte) = pk;
      }
  }
  asm volatile("s_waitcnt lgkmcnt(0)" ::: "memory");
  __builtin_amdgcn_s_barrier();
  ushort_t* dst = (sel == 0) ? qh : (sel == 1) ? kh : vt;
  const int hbase = (bx & 1) * 8;
  #pragma unroll
  for (int it = 0; it < 16; it++) {
    int cg = it*512 + tid;
    int r = cg >> 8, inner = cg & 255;
    int byte;
    if (sel < 2) byte = r*4096 + ((inner*16) ^ (((inner >> 2) & 12) << 3));
    else         byte = r*4096 + ((inner*16) ^ (((inner >> 3) & 7) << 4) ^ ((((inner >> 6) ^ inner) & 1) << 6));
    s16x8 v = *(const s16x8*)((const char*)lds + byte);
    int b = by*4 + (r >> 3), h = hbase + (r & 7);
    *(s16x8*)&dst[(size_t)(b*16 + h)*2048 + inner*8] = v;
  }
}

// ================= proj GEMM: same 256x256 loop, f32 epilogue in 2 passes (swizzled).
__global__ __launch_bounds__(512, 2) void k_gemm_proj(
    const ushort_t* __restrict__ ah, const ushort_t* __restrict__ wh,
    const float* __restrict__ pb, float* __restrict__ out) {
  extern __shared__ __align__(16) ushort_t lds[];
  const int tid = threadIdx.x, w = tid >> 6, lane = tid & 63;
  const int g = lane >> 4, l15 = lane & 15;
  const int wm = w >> 2, wn = w & 3;
  int flat = blockIdx.x;                 // 784 = 8*98, bijective XCD swizzle
  int swz = (flat & 7) * 98 + (flat >> 3);
  int bx = swz & 1, by = swz >> 1;

  const ushort_t* pA = ah + ((size_t)by*256 + (size_t)(2*w)*16 + l15)*512 + g*8;
  const ushort_t* pB = wh + ((size_t)bx*256 + (size_t)(2*w)*16 + l15)*512 + g*8;

  f32x4 acc[8][4];
  #pragma unroll
  for (int r = 0; r < 8; r++)
    #pragma unroll
    for (int c = 0; c < 4; c++) acc[r][c] = (f32x4){0.f, 0.f, 0.f, 0.f};

  gemm256_loop(lds, pA, pB, w, lane, wm, wn, acc);

  // ---- epilogue: two passes of 128 rows x 256 cols f32 (128 KiB), swizzled.
  asm volatile("" ::: "memory");
  #pragma unroll
  for (int p = 0; p < 2; p++) {
    if (p) { asm volatile("" ::: "memory"); __builtin_amdgcn_s_barrier(); }
    if (wm == p) {
      #pragma unroll
      for (int ra = 0; ra < 8; ra++)
        #pragma unroll
        for (int tb = 0; tb < 4; tb++)
          #pragma unroll
          for (int j = 0; j < 4; j++) {
            int row = ra*16 + g*4 + j;          // local 0-127
            int col = wn*64 + tb*16 + l15;
            int byte = (row*1024 + col*4) ^ ((row & 12) << 2) ^ ((row & 8) << 3);
            *(float*)((char*)lds + byte) = acc[ra][tb][j];
          }
    }
    asm volatile("s_waitcnt lgkmcnt(0)" ::: "memory");
    __builtin_amdgcn_s_barrier();
    #pragma unroll
    for (int it = 0; it < 16; it++) {
      int cg = it*512 + tid;
      int row = cg >> 6, c16 = cg & 63;
      int byte = row*1024 + ((c16*16) ^ ((row & 12) << 2) ^ ((row & 8) << 3));
      f32x4 v = *(const f32x4*)((const char*)lds + byte);
      int ncol = bx*256 + c16*4;
      f32x4 pbv = *(const f32x4*)&pb[ncol];
      v = v + pbv;
      *(f32x4*)&out[(size_t)(by*256 + p*128 + row)*512 + ncol] = v;
    }
  }
}

// ---------- kernel 3: per-(b,h) attention, plain bf16, one wave per head-window.
__global__ __launch_bounds__(256) void k_attn(
    const ushort_t* __restrict__ qh, const ushort_t* __restrict__ kh,
    const ushort_t* __restrict__ vt, const float* __restrict__ bias,
    ushort_t* __restrict__ aoh) {
  __shared__ ushort_t plds[4][64*72];
  const int tid = threadIdx.x, w = tid >> 6, lane = tid & 63;
  const int g = lane >> 4, l15 = lane & 15;
  const int gw = blockIdx.x * 4 + w;      // 0 .. 25087
  const int b = gw >> 4, h = gw & 15;
  const size_t base = (size_t)(b*16 + h) * 2048;

  s16x8 qf[4], kf[4];
  #pragma unroll
  for (int t = 0; t < 4; t++) {
    size_t o = base + (size_t)(t*16 + l15)*32 + g*8;
    qf[t] = *(const s16x8*)&qh[o];
    kf[t] = *(const s16x8*)&kh[o];
  }
  s16x8 vf[2][2];
  #pragma unroll
  for (int kt = 0; kt < 2; kt++)
    #pragma unroll
    for (int nt = 0; nt < 2; nt++)
      vf[kt][nt] = *(const s16x8*)&vt[base + (size_t)(nt*16 + l15)*64 + kt*32 + g*8];

  f32x4 s[4][4];
  #pragma unroll
  for (int r = 0; r < 4; r++)
    #pragma unroll
    for (int c = 0; c < 4; c++) s[r][c] = (f32x4){0.f,0.f,0.f,0.f};
  #pragma unroll
  for (int r = 0; r < 4; r++)
    #pragma unroll
    for (int c = 0; c < 4; c++)
      s[r][c] = __builtin_amdgcn_mfma_f32_16x16x32_bf16(qf[r], kf[c], s[r][c], 0, 0, 0);

  const float invs = 0.17677669529663687f;  // 1/sqrt(32)
  const float* bh_ = bias + ((size_t)h << 12);
  #pragma unroll
  for (int r = 0; r < 4; r++)
    #pragma unroll
    for (int c = 0; c < 4; c++)
      #pragma unroll
      for (int j = 0; j < 4; j++) {
        int rr = r*16 + g*4 + j, cc = c*16 + l15;
        s[r][c][j] = s[r][c][j]*invs + bh_[rr*64 + cc];
      }

  #pragma unroll
  for (int r = 0; r < 4; r++)
    #pragma unroll
    for (int j = 0; j < 4; j++) {
      float mx = fmaxf(fmaxf(s[r][0][j], s[r][1][j]), fmaxf(s[r][2][j], s[r][3][j]));
      mx = fmaxf(mx, __shfl_xor(mx, 1));
      mx = fmaxf(mx, __shfl_xor(mx, 2));
      mx = fmaxf(mx, __shfl_xor(mx, 4));
      mx = fmaxf(mx, __shfl_xor(mx, 8));
      float p0 = __expf(s[r][0][j]-mx), p1 = __expf(s[r][1][j]-mx);
      float p2 = __expf(s[r][2][j]-mx), p3 = __expf(s[r][3][j]-mx);
      float sum = p0 + p1 + p2 + p3;
      sum += __shfl_xor(sum, 1);
      sum += __shfl_xor(sum, 2);
      sum += __shfl_xor(sum, 4);
      sum += __shfl_xor(sum, 8);
      float rv = 1.0f / sum;
      s[r][0][j] = p0*rv; s[r][1][j] = p1*rv; s[r][2][j] = p2*rv; s[r][3][j] = p3*rv;
    }

  ushort_t* Pm = plds[w];
  #pragma unroll
  for (int r = 0; r < 4; r++)
    #pragma unroll
    for (int c = 0; c < 4; c++)
      #pragma unroll
      for (int j = 0; j < 4; j++) {
        int rr = r*16 + g*4 + j, cc = c*16 + l15;
        Pm[rr*72 + cc] = f2bf(s[r][c][j]);
      }
  s16x8 pf[4][2];
  #pragma unroll
  for (int ta = 0; ta < 4; ta++)
    #pragma unroll
    for (int kt = 0; kt < 2; kt++)
      pf[ta][kt] = *(const s16x8*)&Pm[(ta*16 + l15)*72 + kt*32 + g*8];

  f32x4 o[4][2];
  #pragma unroll
  for (int ta = 0; ta < 4; ta++)
    #pragma unroll
    for (int nt = 0; nt < 2; nt++) o[ta][nt] = (f32x4){0.f,0.f,0.f,0.f};
  #pragma unroll
  for (int ta = 0; ta < 4; ta++)
    #pragma unroll
    for (int nt = 0; nt < 2; nt++)
      #pragma unroll
      for (int kt = 0; kt < 2; kt++)
        o[ta][nt] = __builtin_amdgcn_mfma_f32_16x16x32_bf16(pf[ta][kt], vf[kt][nt], o[ta][nt], 0, 0, 0);

  #pragma unroll
  for (int ta = 0; ta < 4; ta++)
    #pragma unroll
    for (int nt = 0; nt < 2; nt++)
      #pragma unroll
      for (int j = 0; j < 4; j++) {
        int rr = ta*16 + g*4 + j, dd = nt*16 + l15;
        aoh[((size_t)b*64 + rr)*512 + h*32 + dd] = f2bf(o[ta][nt][j]);
      }
}

extern "C" void kernel_launch(void* const* d_in, const int* in_sizes, int n_in,
                              void* d_out, int out_size, void* d_ws, size_t ws_size,
                              hipStream_t stream) {
  const float* x      = (const float*)d_in[0];
  const float* qkv_w  = (const float*)d_in[1];
  const float* table  = (const float*)d_in[2];
  const float* proj_w = (const float*)d_in[3];
  const float* proj_b = (const float*)d_in[4];
  const int*   rel_idx = (const int*)d_in[5];

  const size_t S1 = S1_ELEMS;
  const size_t need = (4*S1 + 786432 + 262144)*sizeof(ushort_t) + 65536*sizeof(float);
  if (ws_size < need) return;

  ushort_t* qh  = (ushort_t*)d_ws;
  ushort_t* kh  = qh + S1;
  ushort_t* vt  = kh + S1;
  ushort_t* xh  = vt + S1;        // reused as attention-out after QKV GEMM
  ushort_t* wqh = xh + S1;
  ushort_t* wph = wqh + 786432;
  float*    bias = (float*)(wph + 262144);
  ushort_t* aoh = xh;

  hipFuncSetAttribute((const void*)k_gemm_qkv,
                      hipFuncAttributeMaxDynamicSharedMemorySize, 131072);
  hipFuncSetAttribute((const void*)k_gemm_proj,
                      hipFuncAttributeMaxDynamicSharedMemorySize, 131072);

  k_convert_hi<<<2048, 256, 0, stream>>>(x, xh, (long)(S1/4));
  k_convert_hi<<<768, 256, 0, stream>>>(qkv_w, wqh, 196608);
  k_convert_hi<<<256, 256, 0, stream>>>(proj_w, wph, 65536);
  k_bias<<<256, 256, 0, stream>>>(table, rel_idx, bias);
  k_gemm_qkv<<<2352, 512, 131072, stream>>>(xh, wqh, qh, kh, vt);
  k_attn<<<6272, 256, 0, stream>>>(qh, kh, vt, bias, aoh);
  k_gemm_proj<<<784, 512, 131072, stream>>>(aoh, wph, proj_b, (float*)d_out);
}